// Round 4
// baseline (200.111 us; speedup 1.0000x reference)
//
#include <hip/hip_runtime.h>
#include <hip/hip_bf16.h>

#define S_LEN 2048
#define D_MODEL 2048
#define NH 16
#define NKVH 4
#define HD 128
#define KVB 64

typedef __attribute__((ext_vector_type(8))) short bh8;   // 8 bf16 in 4 VGPRs
typedef __attribute__((ext_vector_type(4))) float f4;
typedef unsigned short u16;

#define GAS __attribute__((address_space(1)))
#define LAS __attribute__((address_space(3)))

__device__ __forceinline__ u16 bf16u(float x) {
    __hip_bfloat16 h = __float2bfloat16(x);
    return __builtin_bit_cast(u16, h);
}

// DPP lane ops within 16-lane rows (VALU, no LDS)
template<int C>
__device__ __forceinline__ float dppf(float x) {
    return __builtin_bit_cast(float,
        __builtin_amdgcn_mov_dpp(__builtin_bit_cast(int, x), C, 0xf, 0xf, true));
}
__device__ __forceinline__ float dpp_max16(float m) {
    m = fmaxf(m, dppf<0xB1>(m));
    m = fmaxf(m, dppf<0x4E>(m));
    m = fmaxf(m, dppf<0x141>(m));
    m = fmaxf(m, dppf<0x140>(m));
    return m;
}
__device__ __forceinline__ float dpp_sum16(float s) {
    s += dppf<0xB1>(s);
    s += dppf<0x4E>(s);
    s += dppf<0x141>(s);
    s += dppf<0x140>(s);
    return s;
}

// ---------------- fp32 -> bf16 elementwise (vectorized) ----------------
__global__ __launch_bounds__(256) void cvt_bf16(const float* __restrict__ in,
                                                u16* __restrict__ out, int n) {
    int i = (blockIdx.x * 256 + threadIdx.x) * 4;
    if (i < n) {
        float4 v = *reinterpret_cast<const float4*>(in + i);
        ushort4 o;
        o.x = bf16u(v.x); o.y = bf16u(v.y); o.z = bf16u(v.z); o.w = bf16u(v.w);
        *reinterpret_cast<ushort4*>(out + i) = o;
    }
}

// ---------------- V transpose: VT[h][d][t] = V[h][t][d], bf16 ----------------
__global__ __launch_bounds__(256) void transpose_v(const float* __restrict__ V,
                                                   u16* __restrict__ VT) {
    __shared__ float tile[32][33];
    int h = blockIdx.z;
    int t0 = blockIdx.x * 32, d0 = blockIdx.y * 32;
    int tx = threadIdx.x & 31, ty = threadIdx.x >> 5;
#pragma unroll
    for (int r = 0; r < 4; ++r) {
        int t = ty + r * 8;
        tile[t][tx] = V[(size_t)h * S_LEN * HD + (size_t)(t0 + t) * HD + d0 + tx];
    }
    __syncthreads();
#pragma unroll
    for (int r = 0; r < 4; ++r) {
        int d = ty + r * 8;
        VT[(size_t)h * HD * S_LEN + (size_t)(d0 + d) * S_LEN + t0 + tx] = bf16u(tile[tx][d]);
    }
}

// ---------------- bf16 NT GEMM, 2-phase double-buffered (T3 minimum) --------
// C[m][n] = sum_k A[m][k]*B[n][k]; 128x128 tile, BK=32, 4 waves.
__global__ __launch_bounds__(256) void gemm_nt(const u16* __restrict__ A,
                                               const u16* __restrict__ B,
                                               float* __restrict__ C,
                                               int M, int N, int K) {
    __shared__ u16 As[2][128 * 32];
    __shared__ u16 Bs[2][128 * 32];
    const int tid = threadIdx.x;
    const int wid = tid >> 6, lane = tid & 63;
    const int row0 = blockIdx.y * 128, col0 = blockIdx.x * 128;
    const int wr = (wid >> 1) * 64, wc = (wid & 1) * 64;

    const int strow = wid * 16 + (lane >> 2);
    const int schunk = (lane & 3) * 8;

    f4 acc[4][4] = {};
    const int fr = lane & 15, fk = (lane >> 4) * 8;

#define GSTAGE(b, k0)                                                             \
    {                                                                             \
        __builtin_amdgcn_global_load_lds(                                         \
            (const GAS void*)(A + (size_t)(row0 + strow) * K + (k0) + schunk),    \
            (LAS void*)(As[b] + wid * 512), 16, 0, 0);                            \
        __builtin_amdgcn_global_load_lds(                                         \
            (const GAS void*)(A + (size_t)(row0 + 64 + strow) * K + (k0) + schunk),\
            (LAS void*)(As[b] + 2048 + wid * 512), 16, 0, 0);                     \
        __builtin_amdgcn_global_load_lds(                                         \
            (const GAS void*)(B + (size_t)(col0 + strow) * K + (k0) + schunk),    \
            (LAS void*)(Bs[b] + wid * 512), 16, 0, 0);                            \
        __builtin_amdgcn_global_load_lds(                                         \
            (const GAS void*)(B + (size_t)(col0 + 64 + strow) * K + (k0) + schunk),\
            (LAS void*)(Bs[b] + 2048 + wid * 512), 16, 0, 0);                     \
    }

    GSTAGE(0, 0);
    __syncthreads();

    const int nk = K >> 5;
    for (int t = 0; t < nk; ++t) {
        const int cur = t & 1;
        if (t + 1 < nk) GSTAGE(cur ^ 1, (t + 1) * 32);

        bh8 af[4], bfv[4];
#pragma unroll
        for (int i = 0; i < 4; ++i) {
            af[i]  = *reinterpret_cast<const bh8*>(&As[cur][(wr + i * 16 + fr) * 32 + fk]);
            bfv[i] = *reinterpret_cast<const bh8*>(&Bs[cur][(wc + i * 16 + fr) * 32 + fk]);
        }
#pragma unroll
        for (int i = 0; i < 4; ++i)
#pragma unroll
            for (int j = 0; j < 4; ++j)
                acc[i][j] = __builtin_amdgcn_mfma_f32_16x16x32_bf16(af[i], bfv[j], acc[i][j], 0, 0, 0);
        __syncthreads();
    }
#undef GSTAGE

    const int orow = (lane >> 4) * 4, ocol = lane & 15;
#pragma unroll
    for (int i = 0; i < 4; ++i)
#pragma unroll
        for (int j = 0; j < 4; ++j)
#pragma unroll
            for (int e = 0; e < 4; ++e)
                C[(size_t)(row0 + wr + i * 16 + orow + e) * N + col0 + wc + j * 16 + ocol] = acc[i][j][e];
}

// ---------------- q prep: RMS norm + partial RoPE, emit Q[h][s][d] bf16 ------
__global__ __launch_bounds__(256) void qprep(const float* __restrict__ C1,
                                             const float* __restrict__ cosb,
                                             const float* __restrict__ sinb,
                                             const float* __restrict__ qw,
                                             u16* __restrict__ Qb) {
    int wid = threadIdx.x >> 6, lane = threadIdx.x & 63;
    int id = blockIdx.x * 4 + wid;          // (h,s) index
    int h = id >> 11, s = id & 2047;
    const float* row = C1 + (size_t)s * 4096 + h * 256;
    float v0 = row[lane], v1 = row[lane + 64];
    float ss = v0 * v0 + v1 * v1;
#pragma unroll
    for (int off = 32; off; off >>= 1) ss += __shfl_xor(ss, off, 64);
    float sc = rsqrtf(ss * (1.f / 128.f) + 1e-6f);
    float q0 = v0 * sc * (1.f + qw[lane]);
    float q1 = v1 * sc * (1.f + qw[lane + 64]);
    float part = __shfl_xor(q0, 32, 64);
    float rot = (lane < 32) ? -part : part;
    float c = cosb[s * 64 + lane], sn = sinb[s * 64 + lane];
    float o0 = q0 * c + rot * sn;
    u16* dst = Qb + (size_t)h * S_LEN * HD + (size_t)s * HD;
    dst[lane] = bf16u(o0);
    dst[lane + 64] = bf16u(q1);
}

// ---------------- flash attention (causal, GQA) + sigmoid gate ---------------
// Block = 4 waves = one (head, 64 q-rows). Consecutive block IDs get
// complementary causal lengths so the 2 co-resident blocks per CU balance.
__global__ __launch_bounds__(256) void attn_kernel(const u16* __restrict__ Qb,
                                                   const u16* __restrict__ Kb,
                                                   const u16* __restrict__ VTb,
                                                   const float* __restrict__ C1,
                                                   u16* __restrict__ AO) {
    __shared__ u16 Kt[2][KVB * HD];     // 2 x 16 KiB
    __shared__ u16 Vt[2][HD * KVB];     // 2 x 16 KiB
    __shared__ u16 P_lds[4][16 * 64];   // per-wave, chunk-XOR swizzle

    const int tid = threadIdx.x, wid = tid >> 6, lane = tid & 63;
    const int bid = blockIdx.x;
    // consecutive bids complement: (qb, 31-qb) pairs -> co-resident blocks balance
    const int h = bid >> 5;
    const int r5 = bid & 31;
    const int qb = (r5 & 1) ? (31 - (r5 >> 1)) : (r5 >> 1);
    const int q0w = qb * 64 + wid * 16;
    const int h4 = h >> 2;
    const u16* Qh = Qb + (size_t)h * S_LEN * HD;
    const u16* Kh = Kb + (size_t)h4 * S_LEN * HD;
    const u16* Vh = VTb + (size_t)h4 * HD * S_LEN;
    const int fr = lane & 15, hi4 = lane >> 4, fk = hi4 * 8;
    const int sx = fr & 7;
    constexpr float KS = 0.08838834764831845f * 1.4426950408889634f;  // SCALE*log2e
    constexpr float THR = 11.5f;                                      // ~8 nats

    bh8 qf[4];
#pragma unroll
    for (int kb = 0; kb < 4; ++kb)
        qf[kb] = *reinterpret_cast<const bh8*>(&Qh[(size_t)(q0w + fr) * HD + kb * 32 + fk]);

    f4 acc[8] = {};
    float m_r[4], l_r[4];
#pragma unroll
    for (int j = 0; j < 4; ++j) { m_r[j] = -1e30f; l_r[j] = 0.f; }
    const int myrow = q0w + hi4 * 4;
    u16* Pw = &P_lds[wid][0];

#define STAGE(b, t0)                                                              \
    {                                                                             \
        _Pragma("unroll")                                                         \
        for (int i = 0; i < 4; ++i) {                                             \
            int row = wid * 16 + i * 4 + (lane >> 4);                             \
            int ck = (lane & 15) ^ (row & 7);                                     \
            __builtin_amdgcn_global_load_lds(                                     \
                (const GAS void*)(Kh + (size_t)((t0) + row) * HD + ck * 8),       \
                (LAS void*)(Kt[b] + (wid * 16 + i * 4) * HD), 16, 0, 0);          \
        }                                                                         \
        _Pragma("unroll")                                                         \
        for (int i = 0; i < 4; ++i) {                                             \
            int row = wid * 32 + i * 8 + (lane >> 3);                             \
            int cv = (lane & 7) ^ (row & 7);                                      \
            __builtin_amdgcn_global_load_lds(                                     \
                (const GAS void*)(Vh + (size_t)row * S_LEN + (t0) + cv * 8),      \
                (LAS void*)(Vt[b] + (wid * 32 + i * 8) * KVB), 16, 0, 0);         \
        }                                                                         \
    }

    auto tile_step = [&](int t0, const u16* Ktc, const u16* Vtc, bool masked) {
        f4 sc[4];
#pragma unroll
        for (int nf = 0; nf < 4; ++nf) {
            f4 z = {};
#pragma unroll
            for (int kb = 0; kb < 4; ++kb) {
                bh8 kf = *reinterpret_cast<const bh8*>(
                    &Ktc[(nf * 16 + fr) * HD + (((kb * 4 + hi4) ^ sx) * 8)]);
                z = __builtin_amdgcn_mfma_f32_16x16x32_bf16(qf[kb], kf, z, 0, 0, 0);
            }
#pragma unroll
            for (int j = 0; j < 4; ++j) sc[nf][j] = z[j] * KS;
        }
        if (masked) {
#pragma unroll
            for (int nf = 0; nf < 4; ++nf) {
                int col = t0 + nf * 16 + fr;
#pragma unroll
                for (int j = 0; j < 4; ++j)
                    if (col > myrow + j) sc[nf][j] = -3.0e38f;
            }
        }
        float v[4];
#pragma unroll
        for (int j = 0; j < 4; ++j)
            v[j] = dpp_max16(fmaxf(fmaxf(sc[0][j], sc[1][j]), fmaxf(sc[2][j], sc[3][j])));

        bool need = (v[0] > m_r[0] + THR) || (v[1] > m_r[1] + THR) ||
                    (v[2] > m_r[2] + THR) || (v[3] > m_r[3] + THR);
        if (__any(need)) {
#pragma unroll
            for (int j = 0; j < 4; ++j) {
                float nm = fmaxf(m_r[j], v[j]);
                float corr = exp2f(m_r[j] - nm);
                m_r[j] = nm;
                l_r[j] *= corr;
#pragma unroll
                for (int nf = 0; nf < 8; ++nf) acc[nf][j] *= corr;
            }
        }
#pragma unroll
        for (int j = 0; j < 4; ++j) {
            float rs = 0.f;
#pragma unroll
            for (int nf = 0; nf < 4; ++nf) {
                float p = exp2f(sc[nf][j] - m_r[j]);
                sc[nf][j] = p;
                rs += p;
            }
            l_r[j] += rs;   // per-lane partial; reduced once in epilogue
        }
        // P -> per-wave LDS, [16][64] with chunk^row&7 swizzle
#pragma unroll
        for (int j = 0; j < 4; ++j) {
            int r = hi4 * 4 + j;
            int rb = r * 64, r7 = r & 7;
#pragma unroll
            for (int nf = 0; nf < 4; ++nf) {
                int c = nf * 16 + fr;
                Pw[rb + (((c >> 3) ^ r7) * 8) + (c & 7)] = bf16u(sc[nf][j]);
            }
        }
        asm volatile("s_waitcnt lgkmcnt(0)" ::: "memory");
#pragma unroll
        for (int kk = 0; kk < 2; ++kk) {
            bh8 pa = *reinterpret_cast<const bh8*>(
                &Pw[fr * 64 + (((kk * 4 + hi4) ^ sx) * 8)]);
#pragma unroll
            for (int nf = 0; nf < 8; ++nf) {
                bh8 vf = *reinterpret_cast<const bh8*>(
                    &Vtc[(nf * 16 + fr) * KVB + (((kk * 4 + hi4) ^ sx) * 8)]);
                acc[nf] = __builtin_amdgcn_mfma_f32_16x16x32_bf16(pa, vf, acc[nf], 0, 0, 0);
            }
        }
    };

    STAGE(0, 0);
    __syncthreads();

    for (int t = 0; t < qb; ++t) {
        const int cur = t & 1;
        STAGE(cur ^ 1, (t + 1) * KVB);
        tile_step(t * KVB, Kt[cur], Vt[cur], false);
        __syncthreads();
    }
    tile_step(qb * KVB, Kt[qb & 1], Vt[qb & 1], true);
#undef STAGE

    // epilogue: reduce l, normalize, sigmoid gate, store bf16
    float inv[4];
#pragma unroll
    for (int j = 0; j < 4; ++j)
        inv[j] = 1.0f / dpp_sum16(l_r[j]);

    const int orow = hi4 * 4;
#pragma unroll
    for (int nf = 0; nf < 8; ++nf)
#pragma unroll
        for (int j = 0; j < 4; ++j) {
            int srow = q0w + orow + j;
            int d = nf * 16 + fr;
            float vv = acc[nf][j] * inv[j];
            float g = C1[(size_t)srow * 4096 + h * 256 + 128 + d];
            vv *= 1.f / (1.f + exp2f(-g * 1.4426950408889634f));
            AO[(size_t)srow * D_MODEL + h * HD + d] = bf16u(vv);
        }
}

extern "C" void kernel_launch(void* const* d_in, const int* in_sizes, int n_in,
                              void* d_out, int out_size, void* d_ws, size_t ws_size,
                              hipStream_t stream) {
    const float* hs   = (const float*)d_in[0];
    const float* Kc   = (const float*)d_in[1];
    const float* Vc   = (const float*)d_in[2];
    const float* cosb = (const float*)d_in[3];
    const float* sinb = (const float*)d_in[4];
    const float* Wq   = (const float*)d_in[6];
    const float* Wo   = (const float*)d_in[9];
    const float* qw   = (const float*)d_in[10];
    float* out = (float*)d_out;

    char* ws = (char*)d_ws;
    u16*   x_bf  = (u16*)ws;                          // 8 MiB
    u16*   Wq_bf = (u16*)(ws + (8u << 20));           // 16 MiB
    u16*   Wo_bf = (u16*)(ws + (24u << 20));          // 8 MiB
    u16*   K_bf  = (u16*)(ws + (32u << 20));          // 2 MiB
    u16*   VT_bf = (u16*)(ws + (34u << 20));          // 2 MiB
    float* C1    = (float*)(ws + (36u << 20));        // 32 MiB (q|gate)
    u16*   Qb    = (u16*)(ws + (68u << 20));          // 8 MiB
    u16*   AO    = (u16*)(ws + (76u << 20));          // 8 MiB

    cvt_bf16<<<4096, 256, 0, stream>>>(hs, x_bf, 2048 * 2048);
    cvt_bf16<<<8192, 256, 0, stream>>>(Wq, Wq_bf, 4096 * 2048);
    cvt_bf16<<<4096, 256, 0, stream>>>(Wo, Wo_bf, 2048 * 2048);
    cvt_bf16<<<1024, 256, 0, stream>>>(Kc, K_bf, NKVH * S_LEN * HD);
    transpose_v<<<dim3(64, 4, NKVH), 256, 0, stream>>>(Vc, VT_bf);

    gemm_nt<<<dim3(32, 16), 256, 0, stream>>>(x_bf, Wq_bf, C1, 2048, 4096, 2048);
    qprep<<<8192, 256, 0, stream>>>(C1, cosb, sinb, qw, Qb);
    attn_kernel<<<512, 256, 0, stream>>>(Qb, K_bf, VT_bf, C1, AO);
    gemm_nt<<<dim3(16, 16), 256, 0, stream>>>(AO, Wo_bf, out, 2048, 2048, 2048);
}

// Round 5
// 180.474 us; speedup vs baseline: 1.1088x; 1.1088x over previous
//
#include <hip/hip_runtime.h>
#include <hip/hip_bf16.h>

#define S_LEN 2048
#define D_MODEL 2048
#define NH 16
#define NKVH 4
#define HD 128
#define KVB 64

typedef __attribute__((ext_vector_type(8))) short bh8;   // 8 bf16 in 4 VGPRs
typedef __attribute__((ext_vector_type(4))) float f4;
typedef unsigned short u16;

#define GAS __attribute__((address_space(1)))
#define LAS __attribute__((address_space(3)))

__device__ __forceinline__ u16 bf16u(float x) {
    __hip_bfloat16 h = __float2bfloat16(x);
    return __builtin_bit_cast(u16, h);
}

// DPP lane ops within 16-lane rows (VALU, no LDS)
template<int C>
__device__ __forceinline__ float dppf(float x) {
    return __builtin_bit_cast(float,
        __builtin_amdgcn_mov_dpp(__builtin_bit_cast(int, x), C, 0xf, 0xf, true));
}
__device__ __forceinline__ float dpp_max16(float m) {
    m = fmaxf(m, dppf<0xB1>(m));
    m = fmaxf(m, dppf<0x4E>(m));
    m = fmaxf(m, dppf<0x141>(m));
    m = fmaxf(m, dppf<0x140>(m));
    return m;
}
__device__ __forceinline__ float dpp_sum16(float s) {
    s += dppf<0xB1>(s);
    s += dppf<0x4E>(s);
    s += dppf<0x141>(s);
    s += dppf<0x140>(s);
    return s;
}

// ---------------- fp32 -> bf16 elementwise (vectorized) ----------------
__global__ __launch_bounds__(256) void cvt_bf16(const float* __restrict__ in,
                                                u16* __restrict__ out, int n) {
    int i = (blockIdx.x * 256 + threadIdx.x) * 4;
    if (i < n) {
        float4 v = *reinterpret_cast<const float4*>(in + i);
        ushort4 o;
        o.x = bf16u(v.x); o.y = bf16u(v.y); o.z = bf16u(v.z); o.w = bf16u(v.w);
        *reinterpret_cast<ushort4*>(out + i) = o;
    }
}

// ---------------- V transpose: VT[h][d][t] = V[h][t][d], bf16 ----------------
__global__ __launch_bounds__(256) void transpose_v(const float* __restrict__ V,
                                                   u16* __restrict__ VT) {
    __shared__ float tile[32][33];
    int h = blockIdx.z;
    int t0 = blockIdx.x * 32, d0 = blockIdx.y * 32;
    int tx = threadIdx.x & 31, ty = threadIdx.x >> 5;
#pragma unroll
    for (int r = 0; r < 4; ++r) {
        int t = ty + r * 8;
        tile[t][tx] = V[(size_t)h * S_LEN * HD + (size_t)(t0 + t) * HD + d0 + tx];
    }
    __syncthreads();
#pragma unroll
    for (int r = 0; r < 4; ++r) {
        int d = ty + r * 8;
        VT[(size_t)h * HD * S_LEN + (size_t)(d0 + d) * S_LEN + t0 + tx] = bf16u(tile[tx][d]);
    }
}

// ---------------- bf16 NT GEMM, 2-phase double-buffered (T3 minimum) --------
__global__ __launch_bounds__(256) void gemm_nt(const u16* __restrict__ A,
                                               const u16* __restrict__ B,
                                               float* __restrict__ C,
                                               int M, int N, int K) {
    __shared__ u16 As[2][128 * 32];
    __shared__ u16 Bs[2][128 * 32];
    const int tid = threadIdx.x;
    const int wid = tid >> 6, lane = tid & 63;
    const int row0 = blockIdx.y * 128, col0 = blockIdx.x * 128;
    const int wr = (wid >> 1) * 64, wc = (wid & 1) * 64;

    const int strow = wid * 16 + (lane >> 2);
    const int schunk = (lane & 3) * 8;

    f4 acc[4][4] = {};
    const int fr = lane & 15, fk = (lane >> 4) * 8;

#define GSTAGE(b, k0)                                                             \
    {                                                                             \
        __builtin_amdgcn_global_load_lds(                                         \
            (const GAS void*)(A + (size_t)(row0 + strow) * K + (k0) + schunk),    \
            (LAS void*)(As[b] + wid * 512), 16, 0, 0);                            \
        __builtin_amdgcn_global_load_lds(                                         \
            (const GAS void*)(A + (size_t)(row0 + 64 + strow) * K + (k0) + schunk),\
            (LAS void*)(As[b] + 2048 + wid * 512), 16, 0, 0);                     \
        __builtin_amdgcn_global_load_lds(                                         \
            (const GAS void*)(B + (size_t)(col0 + strow) * K + (k0) + schunk),    \
            (LAS void*)(Bs[b] + wid * 512), 16, 0, 0);                            \
        __builtin_amdgcn_global_load_lds(                                         \
            (const GAS void*)(B + (size_t)(col0 + 64 + strow) * K + (k0) + schunk),\
            (LAS void*)(Bs[b] + 2048 + wid * 512), 16, 0, 0);                     \
    }

    GSTAGE(0, 0);
    __syncthreads();

    const int nk = K >> 5;
    for (int t = 0; t < nk; ++t) {
        const int cur = t & 1;
        if (t + 1 < nk) GSTAGE(cur ^ 1, (t + 1) * 32);

        bh8 af[4], bfv[4];
#pragma unroll
        for (int i = 0; i < 4; ++i) {
            af[i]  = *reinterpret_cast<const bh8*>(&As[cur][(wr + i * 16 + fr) * 32 + fk]);
            bfv[i] = *reinterpret_cast<const bh8*>(&Bs[cur][(wc + i * 16 + fr) * 32 + fk]);
        }
#pragma unroll
        for (int i = 0; i < 4; ++i)
#pragma unroll
            for (int j = 0; j < 4; ++j)
                acc[i][j] = __builtin_amdgcn_mfma_f32_16x16x32_bf16(af[i], bfv[j], acc[i][j], 0, 0, 0);
        __syncthreads();
    }
#undef GSTAGE

    const int orow = (lane >> 4) * 4, ocol = lane & 15;
#pragma unroll
    for (int i = 0; i < 4; ++i)
#pragma unroll
        for (int j = 0; j < 4; ++j)
#pragma unroll
            for (int e = 0; e < 4; ++e)
                C[(size_t)(row0 + wr + i * 16 + orow + e) * N + col0 + wc + j * 16 + ocol] = acc[i][j][e];
}

// ---------------- q prep: RMS norm + partial RoPE, emit Q[h][s][d] bf16 ------
__global__ __launch_bounds__(256) void qprep(const float* __restrict__ C1,
                                             const float* __restrict__ cosb,
                                             const float* __restrict__ sinb,
                                             const float* __restrict__ qw,
                                             u16* __restrict__ Qb) {
    int wid = threadIdx.x >> 6, lane = threadIdx.x & 63;
    int id = blockIdx.x * 4 + wid;          // (h,s) index
    int h = id >> 11, s = id & 2047;
    const float* row = C1 + (size_t)s * 4096 + h * 256;
    float v0 = row[lane], v1 = row[lane + 64];
    float ss = v0 * v0 + v1 * v1;
#pragma unroll
    for (int off = 32; off; off >>= 1) ss += __shfl_xor(ss, off, 64);
    float sc = rsqrtf(ss * (1.f / 128.f) + 1e-6f);
    float q0 = v0 * sc * (1.f + qw[lane]);
    float q1 = v1 * sc * (1.f + qw[lane + 64]);
    float part = __shfl_xor(q0, 32, 64);
    float rot = (lane < 32) ? -part : part;
    float c = cosb[s * 64 + lane], sn = sinb[s * 64 + lane];
    float o0 = q0 * c + rot * sn;
    u16* dst = Qb + (size_t)h * S_LEN * HD + (size_t)s * HD;
    dst[lane] = bf16u(o0);
    dst[lane + 64] = bf16u(q1);
}

// ---------------- flash attention (causal, GQA) + sigmoid gate ---------------
// Block = 4 waves = one (head, 64 q-rows); (b, b+256) complementary qb pairing.
// Single-buffer K/V in LDS (40 KB total -> multi-block residency) with T14
// reg-staged prefetch: global->VGPR issued before compute, LDS publish after.
__global__ __launch_bounds__(256) void attn_kernel(const u16* __restrict__ Qb,
                                                   const u16* __restrict__ Kb,
                                                   const u16* __restrict__ VTb,
                                                   const float* __restrict__ C1,
                                                   u16* __restrict__ AO) {
    __shared__ u16 Kt[KVB * HD];        // 16 KiB
    __shared__ u16 Vt[HD * KVB];        // 16 KiB
    __shared__ u16 P_lds[4][16 * 64];   // 8 KiB, chunk-XOR swizzle

    const int tid = threadIdx.x, wid = tid >> 6, lane = tid & 63;
    const int bid = blockIdx.x;
    // blocks b and b+256 share a CU (fill-then-wrap dispatch) -> complement qb
    const int h = bid & 15;
    const int qb = (bid < 256) ? (bid >> 4) : (31 - ((bid - 256) >> 4));
    const int q0w = qb * 64 + wid * 16;
    const int h4 = h >> 2;
    const u16* Qh = Qb + (size_t)h * S_LEN * HD;
    const u16* Kh = Kb + (size_t)h4 * S_LEN * HD;
    const u16* Vh = VTb + (size_t)h4 * HD * S_LEN;
    const int fr = lane & 15, hi4 = lane >> 4, fk = hi4 * 8;
    const int sx = fr & 7;
    constexpr float KS = 0.08838834764831845f * 1.4426950408889634f;  // SCALE*log2e
    constexpr float THR = 11.5f;                                      // ~8 nats

    bh8 qf[4];
#pragma unroll
    for (int kb = 0; kb < 4; ++kb)
        qf[kb] = *reinterpret_cast<const bh8*>(&Qh[(size_t)(q0w + fr) * HD + kb * 32 + fk]);

    f4 acc[8] = {};
    float m_r[4], l_r[4];
#pragma unroll
    for (int j = 0; j < 4; ++j) { m_r[j] = -1e30f; l_r[j] = 0.f; }
    const int myrow = q0w + hi4 * 4;
    u16* Pw = &P_lds[wid][0];

    bh8 kreg[4], vreg[4];

    // issue global->reg loads for tile at t0 (pre-swizzled source chunks)
    auto load_next = [&](int t0) {
#pragma unroll
        for (int i = 0; i < 4; ++i) {
            int row = wid * 16 + i * 4 + (lane >> 4);
            int ck = (lane & 15) ^ (row & 7);
            kreg[i] = *reinterpret_cast<const bh8*>(Kh + (size_t)(t0 + row) * HD + ck * 8);
        }
#pragma unroll
        for (int i = 0; i < 4; ++i) {
            int row = wid * 32 + i * 8 + (lane >> 3);
            int cv = (lane & 7) ^ (row & 7);
            vreg[i] = *reinterpret_cast<const bh8*>(Vh + (size_t)row * S_LEN + t0 + cv * 8);
        }
    };
    // publish regs -> LDS (linear dest, lane*16B — matches gload_lds layout)
    auto store_next = [&]() {
#pragma unroll
        for (int i = 0; i < 4; ++i)
            *reinterpret_cast<bh8*>(&Kt[(wid * 16 + i * 4) * HD + lane * 8]) = kreg[i];
#pragma unroll
        for (int i = 0; i < 4; ++i)
            *reinterpret_cast<bh8*>(&Vt[(wid * 32 + i * 8) * KVB + lane * 8]) = vreg[i];
    };

    auto tile_step = [&](int t0, bool masked) {
        f4 sc[4];
#pragma unroll
        for (int nf = 0; nf < 4; ++nf) {
            f4 z = {};
#pragma unroll
            for (int kb = 0; kb < 4; ++kb) {
                bh8 kf = *reinterpret_cast<const bh8*>(
                    &Kt[(nf * 16 + fr) * HD + (((kb * 4 + hi4) ^ sx) * 8)]);
                z = __builtin_amdgcn_mfma_f32_16x16x32_bf16(qf[kb], kf, z, 0, 0, 0);
            }
#pragma unroll
            for (int j = 0; j < 4; ++j) sc[nf][j] = z[j] * KS;
        }
        if (masked) {
#pragma unroll
            for (int nf = 0; nf < 4; ++nf) {
                int col = t0 + nf * 16 + fr;
#pragma unroll
                for (int j = 0; j < 4; ++j)
                    if (col > myrow + j) sc[nf][j] = -3.0e38f;
            }
        }
        float v[4];
#pragma unroll
        for (int j = 0; j < 4; ++j)
            v[j] = dpp_max16(fmaxf(fmaxf(sc[0][j], sc[1][j]), fmaxf(sc[2][j], sc[3][j])));

        bool need = (v[0] > m_r[0] + THR) || (v[1] > m_r[1] + THR) ||
                    (v[2] > m_r[2] + THR) || (v[3] > m_r[3] + THR);
        if (__any(need)) {
#pragma unroll
            for (int j = 0; j < 4; ++j) {
                float nm = fmaxf(m_r[j], v[j]);
                float corr = exp2f(m_r[j] - nm);
                m_r[j] = nm;
                l_r[j] *= corr;
#pragma unroll
                for (int nf = 0; nf < 8; ++nf) acc[nf][j] *= corr;
            }
        }
#pragma unroll
        for (int j = 0; j < 4; ++j) {
            float rs = 0.f;
#pragma unroll
            for (int nf = 0; nf < 4; ++nf) {
                float p = exp2f(sc[nf][j] - m_r[j]);
                sc[nf][j] = p;
                rs += p;
            }
            l_r[j] += rs;   // per-lane partial; reduced once in epilogue
        }
        // P -> per-wave LDS, [16][64] with chunk^row&7 swizzle
#pragma unroll
        for (int j = 0; j < 4; ++j) {
            int r = hi4 * 4 + j;
            int rb = r * 64, r7 = r & 7;
#pragma unroll
            for (int nf = 0; nf < 4; ++nf) {
                int c = nf * 16 + fr;
                Pw[rb + (((c >> 3) ^ r7) * 8) + (c & 7)] = bf16u(sc[nf][j]);
            }
        }
        asm volatile("s_waitcnt lgkmcnt(0)" ::: "memory");
#pragma unroll
        for (int kk = 0; kk < 2; ++kk) {
            bh8 pa = *reinterpret_cast<const bh8*>(
                &Pw[fr * 64 + (((kk * 4 + hi4) ^ sx) * 8)]);
#pragma unroll
            for (int nf = 0; nf < 8; ++nf) {
                bh8 vf = *reinterpret_cast<const bh8*>(
                    &Vt[(nf * 16 + fr) * KVB + (((kk * 4 + hi4) ^ sx) * 8)]);
                acc[nf] = __builtin_amdgcn_mfma_f32_16x16x32_bf16(pa, vf, acc[nf], 0, 0, 0);
            }
        }
    };

    load_next(0);
    store_next();
    __syncthreads();

    for (int t = 0; t < qb; ++t) {
        load_next((t + 1) * KVB);       // async prefetch to regs
        tile_step(t * KVB, false);
        __syncthreads();                // all waves done reading Kt/Vt
        store_next();                   // publish tile t+1
        __syncthreads();
    }
    tile_step(qb * KVB, true);

    // epilogue: reduce l, normalize, sigmoid gate, store bf16
    float inv[4];
#pragma unroll
    for (int j = 0; j < 4; ++j)
        inv[j] = 1.0f / dpp_sum16(l_r[j]);

    const int orow = hi4 * 4;
#pragma unroll
    for (int nf = 0; nf < 8; ++nf)
#pragma unroll
        for (int j = 0; j < 4; ++j) {
            int srow = q0w + orow + j;
            int d = nf * 16 + fr;
            float vv = acc[nf][j] * inv[j];
            float g = C1[(size_t)srow * 4096 + h * 256 + 128 + d];
            vv *= 1.f / (1.f + exp2f(-g * 1.4426950408889634f));
            AO[(size_t)srow * D_MODEL + h * HD + d] = bf16u(vv);
        }
}

extern "C" void kernel_launch(void* const* d_in, const int* in_sizes, int n_in,
                              void* d_out, int out_size, void* d_ws, size_t ws_size,
                              hipStream_t stream) {
    const float* hs   = (const float*)d_in[0];
    const float* Kc   = (const float*)d_in[1];
    const float* Vc   = (const float*)d_in[2];
    const float* cosb = (const float*)d_in[3];
    const float* sinb = (const float*)d_in[4];
    const float* Wq   = (const float*)d_in[6];
    const float* Wo   = (const float*)d_in[9];
    const float* qw   = (const float*)d_in[10];
    float* out = (float*)d_out;

    char* ws = (char*)d_ws;
    u16*   x_bf  = (u16*)ws;                          // 8 MiB
    u16*   Wq_bf = (u16*)(ws + (8u << 20));           // 16 MiB
    u16*   Wo_bf = (u16*)(ws + (24u << 20));          // 8 MiB
    u16*   K_bf  = (u16*)(ws + (32u << 20));          // 2 MiB
    u16*   VT_bf = (u16*)(ws + (34u << 20));          // 2 MiB
    float* C1    = (float*)(ws + (36u << 20));        // 32 MiB (q|gate)
    u16*   Qb    = (u16*)(ws + (68u << 20));          // 8 MiB
    u16*   AO    = (u16*)(ws + (76u << 20));          // 8 MiB

    cvt_bf16<<<4096, 256, 0, stream>>>(hs, x_bf, 2048 * 2048);
    cvt_bf16<<<8192, 256, 0, stream>>>(Wq, Wq_bf, 4096 * 2048);
    cvt_bf16<<<4096, 256, 0, stream>>>(Wo, Wo_bf, 2048 * 2048);
    cvt_bf16<<<1024, 256, 0, stream>>>(Kc, K_bf, NKVH * S_LEN * HD);
    transpose_v<<<dim3(64, 4, NKVH), 256, 0, stream>>>(Vc, VT_bf);

    gemm_nt<<<dim3(32, 16), 256, 0, stream>>>(x_bf, Wq_bf, C1, 2048, 4096, 2048);
    qprep<<<8192, 256, 0, stream>>>(C1, cosb, sinb, qw, Qb);
    attn_kernel<<<512, 256, 0, stream>>>(Qb, K_bf, VT_bf, C1, AO);
    gemm_nt<<<dim3(16, 16), 256, 0, stream>>>(AO, Wo_bf, out, 2048, 2048, 2048);
}

// Round 6
// 179.228 us; speedup vs baseline: 1.1165x; 1.0070x over previous
//
#include <hip/hip_runtime.h>
#include <hip/hip_bf16.h>

#define S_LEN 2048
#define D_MODEL 2048
#define NH 16
#define NKVH 4
#define HD 128
#define KVB 64

typedef __attribute__((ext_vector_type(8))) short bh8;   // 8 bf16 in 4 VGPRs
typedef __attribute__((ext_vector_type(4))) float f4;
typedef unsigned short u16;

#define GAS __attribute__((address_space(1)))
#define LAS __attribute__((address_space(3)))

__device__ __forceinline__ u16 bf16u(float x) {
    __hip_bfloat16 h = __float2bfloat16(x);
    return __builtin_bit_cast(u16, h);
}

// DPP lane ops within 16-lane rows (VALU, no LDS)
template<int C>
__device__ __forceinline__ float dppf(float x) {
    return __builtin_bit_cast(float,
        __builtin_amdgcn_mov_dpp(__builtin_bit_cast(int, x), C, 0xf, 0xf, true));
}
__device__ __forceinline__ float dpp_max16(float m) {
    m = fmaxf(m, dppf<0xB1>(m));
    m = fmaxf(m, dppf<0x4E>(m));
    m = fmaxf(m, dppf<0x141>(m));
    m = fmaxf(m, dppf<0x140>(m));
    return m;
}
__device__ __forceinline__ float dpp_sum16(float s) {
    s += dppf<0xB1>(s);
    s += dppf<0x4E>(s);
    s += dppf<0x141>(s);
    s += dppf<0x140>(s);
    return s;
}

// ---------------- fp32 -> bf16 elementwise (vectorized) ----------------
__global__ __launch_bounds__(256) void cvt_bf16(const float* __restrict__ in,
                                                u16* __restrict__ out, int n) {
    int i = (blockIdx.x * 256 + threadIdx.x) * 4;
    if (i < n) {
        float4 v = *reinterpret_cast<const float4*>(in + i);
        ushort4 o;
        o.x = bf16u(v.x); o.y = bf16u(v.y); o.z = bf16u(v.z); o.w = bf16u(v.w);
        *reinterpret_cast<ushort4*>(out + i) = o;
    }
}

// ---------------- V transpose: VT[h][d][t] = V[h][t][d], bf16 ----------------
__global__ __launch_bounds__(256) void transpose_v(const float* __restrict__ V,
                                                   u16* __restrict__ VT) {
    __shared__ float tile[32][33];
    int h = blockIdx.z;
    int t0 = blockIdx.x * 32, d0 = blockIdx.y * 32;
    int tx = threadIdx.x & 31, ty = threadIdx.x >> 5;
#pragma unroll
    for (int r = 0; r < 4; ++r) {
        int t = ty + r * 8;
        tile[t][tx] = V[(size_t)h * S_LEN * HD + (size_t)(t0 + t) * HD + d0 + tx];
    }
    __syncthreads();
#pragma unroll
    for (int r = 0; r < 4; ++r) {
        int d = ty + r * 8;
        VT[(size_t)h * HD * S_LEN + (size_t)(d0 + d) * S_LEN + t0 + tx] = bf16u(tile[tx][d]);
    }
}

// ---------------- bf16 NT GEMM, 2-phase double-buffered --------
__global__ __launch_bounds__(256) void gemm_nt(const u16* __restrict__ A,
                                               const u16* __restrict__ B,
                                               float* __restrict__ C,
                                               int M, int N, int K) {
    __shared__ u16 As[2][128 * 32];
    __shared__ u16 Bs[2][128 * 32];
    const int tid = threadIdx.x;
    const int wid = tid >> 6, lane = tid & 63;
    const int row0 = blockIdx.y * 128, col0 = blockIdx.x * 128;
    const int wr = (wid >> 1) * 64, wc = (wid & 1) * 64;

    const int strow = wid * 16 + (lane >> 2);
    const int schunk = (lane & 3) * 8;

    f4 acc[4][4] = {};
    const int fr = lane & 15, fk = (lane >> 4) * 8;

#define GSTAGE(b, k0)                                                             \
    {                                                                             \
        __builtin_amdgcn_global_load_lds(                                         \
            (const GAS void*)(A + (size_t)(row0 + strow) * K + (k0) + schunk),    \
            (LAS void*)(As[b] + wid * 512), 16, 0, 0);                            \
        __builtin_amdgcn_global_load_lds(                                         \
            (const GAS void*)(A + (size_t)(row0 + 64 + strow) * K + (k0) + schunk),\
            (LAS void*)(As[b] + 2048 + wid * 512), 16, 0, 0);                     \
        __builtin_amdgcn_global_load_lds(                                         \
            (const GAS void*)(B + (size_t)(col0 + strow) * K + (k0) + schunk),    \
            (LAS void*)(Bs[b] + wid * 512), 16, 0, 0);                            \
        __builtin_amdgcn_global_load_lds(                                         \
            (const GAS void*)(B + (size_t)(col0 + 64 + strow) * K + (k0) + schunk),\
            (LAS void*)(Bs[b] + 2048 + wid * 512), 16, 0, 0);                     \
    }

    GSTAGE(0, 0);
    __syncthreads();

    const int nk = K >> 5;
    for (int t = 0; t < nk; ++t) {
        const int cur = t & 1;
        if (t + 1 < nk) GSTAGE(cur ^ 1, (t + 1) * 32);

        bh8 af[4], bfv[4];
#pragma unroll
        for (int i = 0; i < 4; ++i) {
            af[i]  = *reinterpret_cast<const bh8*>(&As[cur][(wr + i * 16 + fr) * 32 + fk]);
            bfv[i] = *reinterpret_cast<const bh8*>(&Bs[cur][(wc + i * 16 + fr) * 32 + fk]);
        }
#pragma unroll
        for (int i = 0; i < 4; ++i)
#pragma unroll
            for (int j = 0; j < 4; ++j)
                acc[i][j] = __builtin_amdgcn_mfma_f32_16x16x32_bf16(af[i], bfv[j], acc[i][j], 0, 0, 0);
        __syncthreads();
    }
#undef GSTAGE

    const int orow = (lane >> 4) * 4, ocol = lane & 15;
#pragma unroll
    for (int i = 0; i < 4; ++i)
#pragma unroll
        for (int j = 0; j < 4; ++j)
#pragma unroll
            for (int e = 0; e < 4; ++e)
                C[(size_t)(row0 + wr + i * 16 + orow + e) * N + col0 + wc + j * 16 + ocol] = acc[i][j][e];
}

// ---------------- q prep: RMS norm + partial RoPE, emit Q[h][s][d] bf16 ------
__global__ __launch_bounds__(256) void qprep(const float* __restrict__ C1,
                                             const float* __restrict__ cosb,
                                             const float* __restrict__ sinb,
                                             const float* __restrict__ qw,
                                             u16* __restrict__ Qb) {
    int wid = threadIdx.x >> 6, lane = threadIdx.x & 63;
    int id = blockIdx.x * 4 + wid;          // (h,s) index
    int h = id >> 11, s = id & 2047;
    const float* row = C1 + (size_t)s * 4096 + h * 256;
    float v0 = row[lane], v1 = row[lane + 64];
    float ss = v0 * v0 + v1 * v1;
#pragma unroll
    for (int off = 32; off; off >>= 1) ss += __shfl_xor(ss, off, 64);
    float sc = rsqrtf(ss * (1.f / 128.f) + 1e-6f);
    float q0 = v0 * sc * (1.f + qw[lane]);
    float q1 = v1 * sc * (1.f + qw[lane + 64]);
    float part = __shfl_xor(q0, 32, 64);
    float rot = (lane < 32) ? -part : part;
    float c = cosb[s * 64 + lane], sn = sinb[s * 64 + lane];
    float o0 = q0 * c + rot * sn;
    u16* dst = Qb + (size_t)h * S_LEN * HD + (size_t)s * HD;
    dst[lane] = bf16u(o0);
    dst[lane + 64] = bf16u(q1);
}

// ---------------- flash attention, KV-split (flash-decoding) -----------------
// Block = 4 waves = (head, 64 q-rows, kv-half). 1024 blocks, LPT order.
// Writes unnormalized O partial (fp32) + per-row (m, l) in log2 domain.
__global__ __launch_bounds__(256) void attn_kernel(const u16* __restrict__ Qb,
                                                   const u16* __restrict__ Kb,
                                                   const u16* __restrict__ VTb,
                                                   float* __restrict__ O0p,
                                                   float* __restrict__ O1p,
                                                   float* __restrict__ M0,
                                                   float* __restrict__ L0,
                                                   float* __restrict__ M1,
                                                   float* __restrict__ L1) {
    __shared__ u16 Kt[KVB * HD];        // 16 KiB
    __shared__ u16 Vt[HD * KVB];        // 16 KiB
    __shared__ u16 P_lds[4][16 * 64];   // 8 KiB, chunk-XOR swizzle

    const int tid = threadIdx.x, wid = tid >> 6, lane = tid & 63;
    const int bid = blockIdx.x;          // 0..1023
    const int half = bid & 1;
    const int rest = bid >> 1;           // 0..511
    const int h = rest & 15;
    const int qb = 31 - (rest >> 4);     // LPT: longest blocks dispatched first
    const int q0w = qb * 64 + wid * 16;
    const int h4 = h >> 2;
    const u16* Qh = Qb + (size_t)h * S_LEN * HD;
    const u16* Kh = Kb + (size_t)h4 * S_LEN * HD;
    const u16* Vh = VTb + (size_t)h4 * HD * S_LEN;
    const int fr = lane & 15, hi4 = lane >> 4, fk = hi4 * 8;
    const int sx = fr & 7;
    constexpr float KS = 0.08838834764831845f * 1.4426950408889634f;  // SCALE*log2e
    constexpr float THR = 11.5f;                                      // ~8 nats

    const int nt0 = (qb + 1) >> 1;
    const int tb = half ? nt0 : 0;
    const int te = half ? (qb + 1) : nt0;

    bh8 qf[4];
#pragma unroll
    for (int kb = 0; kb < 4; ++kb)
        qf[kb] = *reinterpret_cast<const bh8*>(&Qh[(size_t)(q0w + fr) * HD + kb * 32 + fk]);

    f4 acc[8] = {};
    float m_r[4], l_r[4];
#pragma unroll
    for (int j = 0; j < 4; ++j) { m_r[j] = -1e30f; l_r[j] = 0.f; }
    const int myrow = q0w + hi4 * 4;
    u16* Pw = &P_lds[wid][0];

    bh8 kreg[4], vreg[4];

    auto load_next = [&](int t0) {
#pragma unroll
        for (int i = 0; i < 4; ++i) {
            int row = wid * 16 + i * 4 + (lane >> 4);
            int ck = (lane & 15) ^ (row & 7);
            kreg[i] = *reinterpret_cast<const bh8*>(Kh + (size_t)(t0 + row) * HD + ck * 8);
        }
#pragma unroll
        for (int i = 0; i < 4; ++i) {
            int row = wid * 32 + i * 8 + (lane >> 3);
            int cv = (lane & 7) ^ (row & 7);
            vreg[i] = *reinterpret_cast<const bh8*>(Vh + (size_t)row * S_LEN + t0 + cv * 8);
        }
    };
    auto store_next = [&]() {
#pragma unroll
        for (int i = 0; i < 4; ++i)
            *reinterpret_cast<bh8*>(&Kt[(wid * 16 + i * 4) * HD + lane * 8]) = kreg[i];
#pragma unroll
        for (int i = 0; i < 4; ++i)
            *reinterpret_cast<bh8*>(&Vt[(wid * 32 + i * 8) * KVB + lane * 8]) = vreg[i];
    };

    auto tile_step = [&](int t0, bool masked) {
        f4 sc[4];
#pragma unroll
        for (int nf = 0; nf < 4; ++nf) {
            f4 z = {};
#pragma unroll
            for (int kb = 0; kb < 4; ++kb) {
                bh8 kf = *reinterpret_cast<const bh8*>(
                    &Kt[(nf * 16 + fr) * HD + (((kb * 4 + hi4) ^ sx) * 8)]);
                z = __builtin_amdgcn_mfma_f32_16x16x32_bf16(qf[kb], kf, z, 0, 0, 0);
            }
#pragma unroll
            for (int j = 0; j < 4; ++j) sc[nf][j] = z[j] * KS;
        }
        if (masked) {
#pragma unroll
            for (int nf = 0; nf < 4; ++nf) {
                int col = t0 + nf * 16 + fr;
#pragma unroll
                for (int j = 0; j < 4; ++j)
                    if (col > myrow + j) sc[nf][j] = -3.0e38f;
            }
        }
        float v[4];
#pragma unroll
        for (int j = 0; j < 4; ++j)
            v[j] = dpp_max16(fmaxf(fmaxf(sc[0][j], sc[1][j]), fmaxf(sc[2][j], sc[3][j])));

        bool need = (v[0] > m_r[0] + THR) || (v[1] > m_r[1] + THR) ||
                    (v[2] > m_r[2] + THR) || (v[3] > m_r[3] + THR);
        if (__any(need)) {
#pragma unroll
            for (int j = 0; j < 4; ++j) {
                float nm = fmaxf(m_r[j], v[j]);
                float corr = exp2f(m_r[j] - nm);
                m_r[j] = nm;
                l_r[j] *= corr;
#pragma unroll
                for (int nf = 0; nf < 8; ++nf) acc[nf][j] *= corr;
            }
        }
#pragma unroll
        for (int j = 0; j < 4; ++j) {
            float rs = 0.f;
#pragma unroll
            for (int nf = 0; nf < 4; ++nf) {
                float p = exp2f(sc[nf][j] - m_r[j]);
                sc[nf][j] = p;
                rs += p;
            }
            l_r[j] += rs;   // per-lane partial; reduced in epilogue
        }
#pragma unroll
        for (int j = 0; j < 4; ++j) {
            int r = hi4 * 4 + j;
            int rb = r * 64, r7 = r & 7;
#pragma unroll
            for (int nf = 0; nf < 4; ++nf) {
                int c = nf * 16 + fr;
                Pw[rb + (((c >> 3) ^ r7) * 8) + (c & 7)] = bf16u(sc[nf][j]);
            }
        }
        asm volatile("s_waitcnt lgkmcnt(0)" ::: "memory");
#pragma unroll
        for (int kk = 0; kk < 2; ++kk) {
            bh8 pa = *reinterpret_cast<const bh8*>(
                &Pw[fr * 64 + (((kk * 4 + hi4) ^ sx) * 8)]);
#pragma unroll
            for (int nf = 0; nf < 8; ++nf) {
                bh8 vf = *reinterpret_cast<const bh8*>(
                    &Vt[(nf * 16 + fr) * KVB + (((kk * 4 + hi4) ^ sx) * 8)]);
                acc[nf] = __builtin_amdgcn_mfma_f32_16x16x32_bf16(pa, vf, acc[nf], 0, 0, 0);
            }
        }
    };

    if (tb < te) {
        load_next(tb * KVB);
        store_next();
        __syncthreads();
        for (int t = tb; t < te - 1; ++t) {
            load_next((t + 1) * KVB);
            tile_step(t * KVB, false);
            __syncthreads();
            store_next();
            __syncthreads();
        }
        tile_step((te - 1) * KVB, (te - 1) == qb);
    }

    // epilogue: reduce l, store unnormalized partials
    float* Op = half ? O1p : O0p;
    float* Mp = half ? M1 : M0;
    float* Lp = half ? L1 : L0;

    float lred[4];
#pragma unroll
    for (int j = 0; j < 4; ++j) lred[j] = dpp_sum16(l_r[j]);
    if (fr == 0) {
#pragma unroll
        for (int j = 0; j < 4; ++j) {
            int srow = q0w + hi4 * 4 + j;
            Mp[h * S_LEN + srow] = m_r[j];
            Lp[h * S_LEN + srow] = lred[j];
        }
    }
    const int orow = hi4 * 4;
#pragma unroll
    for (int nf = 0; nf < 8; ++nf)
#pragma unroll
        for (int j = 0; j < 4; ++j) {
            int srow = q0w + orow + j;
            Op[(size_t)h * S_LEN * HD + (size_t)srow * HD + nf * 16 + fr] = acc[nf][j];
        }
}

// ---------------- combine: merge 2 KV-halves, gate, emit bf16 AO -------------
__global__ __launch_bounds__(256) void attn_combine(const float* __restrict__ O0p,
                                                    const float* __restrict__ O1p,
                                                    const float* __restrict__ M0,
                                                    const float* __restrict__ L0,
                                                    const float* __restrict__ M1,
                                                    const float* __restrict__ L1,
                                                    const float* __restrict__ C1,
                                                    u16* __restrict__ AO) {
    int idx = blockIdx.x * 256 + threadIdx.x;   // 0 .. 16*2048*32-1
    int d4 = idx & 31;
    int s  = (idx >> 5) & 2047;
    int h  = idx >> 16;
    int row = h * S_LEN + s;
    float m0 = M0[row], l0 = L0[row], m1 = M1[row], l1 = L1[row];
    float m = fmaxf(m0, m1);
    float a = exp2f(m0 - m), b = exp2f(m1 - m);
    float inv = 1.f / (a * l0 + b * l1);
    const float4 o0 = *reinterpret_cast<const float4*>(O0p + (size_t)row * HD + d4 * 4);
    const float4 o1 = *reinterpret_cast<const float4*>(O1p + (size_t)row * HD + d4 * 4);
    const float4 g  = *reinterpret_cast<const float4*>(C1 + (size_t)s * 4096 + h * 256 + 128 + d4 * 4);
    constexpr float L2E = 1.4426950408889634f;
    ushort4 o;
    o.x = bf16u((a * o0.x + b * o1.x) * inv / (1.f + exp2f(-g.x * L2E)));
    o.y = bf16u((a * o0.y + b * o1.y) * inv / (1.f + exp2f(-g.y * L2E)));
    o.z = bf16u((a * o0.z + b * o1.z) * inv / (1.f + exp2f(-g.z * L2E)));
    o.w = bf16u((a * o0.w + b * o1.w) * inv / (1.f + exp2f(-g.w * L2E)));
    *reinterpret_cast<ushort4*>(AO + (size_t)s * D_MODEL + h * HD + d4 * 4) = o;
}

extern "C" void kernel_launch(void* const* d_in, const int* in_sizes, int n_in,
                              void* d_out, int out_size, void* d_ws, size_t ws_size,
                              hipStream_t stream) {
    const float* hs   = (const float*)d_in[0];
    const float* Kc   = (const float*)d_in[1];
    const float* Vc   = (const float*)d_in[2];
    const float* cosb = (const float*)d_in[3];
    const float* sinb = (const float*)d_in[4];
    const float* Wq   = (const float*)d_in[6];
    const float* Wo   = (const float*)d_in[9];
    const float* qw   = (const float*)d_in[10];
    float* out = (float*)d_out;

    char* ws = (char*)d_ws;
    u16*   x_bf  = (u16*)ws;                          // 8 MiB   (dead after gemm1)
    u16*   Wq_bf = (u16*)(ws + (8u << 20));           // 16 MiB  (dead after gemm1)
    u16*   Wo_bf = (u16*)(ws + (24u << 20));          // 8 MiB   (live till gemm2)
    u16*   K_bf  = (u16*)(ws + (32u << 20));          // 2 MiB
    u16*   VT_bf = (u16*)(ws + (34u << 20));          // 2 MiB
    float* C1    = (float*)(ws + (36u << 20));        // 32 MiB (q|gate; live till combine)
    u16*   Qb    = (u16*)(ws + (68u << 20));          // 8 MiB
    u16*   AO    = (u16*)(ws + (76u << 20));          // 8 MiB
    float* O0p   = (float*)ws;                        // 16 MiB, reuses x_bf+Wq_bf[0:8M]
    float* O1p   = (float*)(ws + (84u << 20));        // 16 MiB
    float* M0    = (float*)(ws + (100u << 20));       // 128 KiB each
    float* L0    = M0 + NH * S_LEN;
    float* M1    = L0 + NH * S_LEN;
    float* L1    = M1 + NH * S_LEN;                   // total 100.5 MiB

    cvt_bf16<<<4096, 256, 0, stream>>>(hs, x_bf, 2048 * 2048);
    cvt_bf16<<<8192, 256, 0, stream>>>(Wq, Wq_bf, 4096 * 2048);
    cvt_bf16<<<4096, 256, 0, stream>>>(Wo, Wo_bf, 2048 * 2048);
    cvt_bf16<<<1024, 256, 0, stream>>>(Kc, K_bf, NKVH * S_LEN * HD);
    transpose_v<<<dim3(64, 4, NKVH), 256, 0, stream>>>(Vc, VT_bf);

    gemm_nt<<<dim3(32, 16), 256, 0, stream>>>(x_bf, Wq_bf, C1, 2048, 4096, 2048);
    qprep<<<8192, 256, 0, stream>>>(C1, cosb, sinb, qw, Qb);
    attn_kernel<<<1024, 256, 0, stream>>>(Qb, K_bf, VT_bf, O0p, O1p, M0, L0, M1, L1);
    attn_combine<<<4096, 256, 0, stream>>>(O0p, O1p, M0, L0, M1, L1, C1, AO);
    gemm_nt<<<dim3(16, 16), 256, 0, stream>>>(AO, Wo_bf, out, 2048, 2048, 2048);
}